// Round 13
// baseline (193.711 us; speedup 1.0000x reference)
//
#include <hip/hip_runtime.h>
#include <hip/hip_bf16.h>
#include <hip/hip_cooperative_groups.h>

#define SAMPLE 512
#define GDIM   510
#define HID    128
#define LATENT 32
#define HID2   256
#define TB     32      // batch rows per block = two 16-row m-tiles
#define NT     512     // 8 waves

typedef unsigned short u16;
typedef unsigned int   u32;
typedef __attribute__((ext_vector_type(8))) short s16x8;
typedef __attribute__((ext_vector_type(4))) float f32x4;

// packed-weight regions (u16 element offsets within one copy)
// layout per matrix: [nt][kt][lane 0..63][j 0..7], chunk = 8 u16 = 16 B
#define WGP_OFF   0                         // gather W: N=512(510) K=512
#define W1P_OFF   (WGP_OFF  + 32*16*512)    // w1:  N=128 K=512(510)
#define W2P_OFF   (W1P_OFF  + 8*16*512)     // w2:  N=32  K=128
#define DW1P_OFF  (W2P_OFF  + 2*4*512)      // dw1: N=128 K=32
#define DW2P_OFF  (DW1P_OFF + 8*1*512)      // dw2: N=256 K=128
#define DW3P_OFF  (DW2P_OFF + 16*4*512)     // dw3: N=512 K=256
#define PACK_U16  (DW3P_OFF + 32*8*512)     // 499712 u16 per copy
#define NCHUNK    (PACK_U16 / 8)            // 62464 chunks per copy
#define COPY_U16  (1u << 19)                // 1 MiB stride per copy

__device__ __forceinline__ u16 f2b(float f) {
    union { float f; u32 i; } v; v.f = f;
    return (u16)((v.i + 0x7FFFu + ((v.i >> 16) & 1u)) >> 16);
}

// ---------------- build one 16-B packed chunk (no early returns) ----------------
__device__ __forceinline__ void build_chunk(
    int c, u16* __restrict__ wsc,
    const float* __restrict__ w1, const float* __restrict__ w2,
    const float* __restrict__ dw1, const float* __restrict__ dw2,
    const float* __restrict__ dw3,
    const float* __restrict__ gw, const float* __restrict__ mask,
    const int* __restrict__ idx, int G, int K)
{
    u16 tmp[8];
    if (c < W1P_OFF / 8) {                 // gather-W region
        int lane = c & 63;
        int kt   = (c >> 6) & 15;
        int nt   = (c >> 6) >> 4;
        int g    = nt * 16 + (lane & 15);
        int k0   = kt * 32 + (lane >> 4) * 8;
        #pragma unroll
        for (int j = 0; j < 8; ++j) tmp[j] = 0;
        if (g < G) {
            const int*   idxr = idx  + (size_t)g * K;
            const float* gwr  = gw   + (size_t)g * K;
            const float* mr   = mask + (size_t)g * K;
            int t = 0;
            for (; t + 4 <= K; t += 4) {
                int   j0 = idxr[t]     - k0, j1 = idxr[t + 1] - k0;
                int   j2 = idxr[t + 2] - k0, j3 = idxr[t + 3] - k0;
                float m0 = mr[t],     m1 = mr[t + 1];
                float m2 = mr[t + 2], m3 = mr[t + 3];
                float v0 = gwr[t],     v1 = gwr[t + 1];
                float v2 = gwr[t + 2], v3 = gwr[t + 3];
                if ((unsigned)j0 < 8u && m0 > 0.f) tmp[j0] = f2b(v0 * m0);
                if ((unsigned)j1 < 8u && m1 > 0.f) tmp[j1] = f2b(v1 * m1);
                if ((unsigned)j2 < 8u && m2 > 0.f) tmp[j2] = f2b(v2 * m2);
                if ((unsigned)j3 < 8u && m3 > 0.f) tmp[j3] = f2b(v3 * m3);
            }
            for (; t < K; ++t) {
                int j = idxr[t] - k0;
                float m = mr[t];
                if ((unsigned)j < 8u && m > 0.f) tmp[j] = f2b(gwr[t] * m);
            }
        }
    } else {
        const float* W; int Kd, Nd, KT, base;
        if      (c < W2P_OFF / 8)  { W = w1;  Kd = GDIM;   Nd = HID;    KT = 16; base = W1P_OFF / 8; }
        else if (c < DW1P_OFF / 8) { W = w2;  Kd = HID;    Nd = LATENT; KT = 4;  base = W2P_OFF / 8; }
        else if (c < DW2P_OFF / 8) { W = dw1; Kd = LATENT; Nd = HID;    KT = 1;  base = DW1P_OFF / 8; }
        else if (c < DW3P_OFF / 8) { W = dw2; Kd = HID;    Nd = HID2;   KT = 4;  base = DW2P_OFF / 8; }
        else                       { W = dw3; Kd = HID2;   Nd = SAMPLE; KT = 8;  base = DW3P_OFF / 8; }
        int c2   = c - base;
        int lane = c2 & 63;
        int kt   = (c2 >> 6) % KT;
        int nt   = (c2 >> 6) / KT;
        int n    = nt * 16 + (lane & 15);
        int k0   = kt * 32 + (lane >> 4) * 8;
        #pragma unroll
        for (int j = 0; j < 8; ++j) {
            int k = k0 + j;
            float v = (k < Kd && n < Nd) ? W[(size_t)k * Nd + n] : 0.f;
            tmp[j] = f2b(v);
        }
    }
    *(s16x8*)(wsc + (size_t)c * 8) = *(s16x8*)tmp;
}

// ---------------- generic MFMA phase: M=32 (2 m-tiles per wave, b reused) ----------------
template<int KT, int NTN, int TPW>
__device__ __forceinline__ void mfma_phase(
    int wave, int lane,
    const u16* inl, int sin,
    const u16* __restrict__ pW,
    const float* bias,
    u16* outl, int sout)
{
    if (NTN < 8 && wave >= NTN) return;
    const u16* arow0 = inl + (lane & 15) * sin + (lane >> 4) * 8;
    const u16* arow1 = arow0 + 16 * sin;
    f32x4 acc[TPW][2];
    #pragma unroll
    for (int i = 0; i < TPW; ++i) {
        acc[i][0] = (f32x4){0.f, 0.f, 0.f, 0.f};
        acc[i][1] = (f32x4){0.f, 0.f, 0.f, 0.f};
    }
    #pragma unroll
    for (int kt = 0; kt < KT; ++kt) {
        s16x8 a0 = *(const s16x8*)(arow0 + kt * 32);
        s16x8 a1 = *(const s16x8*)(arow1 + kt * 32);
        #pragma unroll
        for (int i = 0; i < TPW; ++i) {
            int nt = wave + 8 * i;
            s16x8 b = *(const s16x8*)(pW + (size_t)((nt * KT + kt) * 64 + lane) * 8);
            acc[i][0] = __builtin_amdgcn_mfma_f32_16x16x32_bf16(a0, b, acc[i][0], 0, 0, 0);
            acc[i][1] = __builtin_amdgcn_mfma_f32_16x16x32_bf16(a1, b, acc[i][1], 0, 0, 0);
        }
    }
    #pragma unroll
    for (int i = 0; i < TPW; ++i) {
        int nt = wave + 8 * i;
        int col = nt * 16 + (lane & 15);
        float bs = bias[col];
        #pragma unroll
        for (int mt = 0; mt < 2; ++mt) {
            #pragma unroll
            for (int r = 0; r < 4; ++r) {
                int row = mt * 16 + (lane >> 4) * 4 + r;
                float v = acc[i][mt][r] + bs;
                outl[row * sout + col] = f2b(v > 0.f ? v : 0.f);
            }
        }
    }
}

// ---------------- single fused cooperative kernel ----------------
// LDS union overlay (u16 offsets):
//   region0 [0,18432): xs [32][520] (phases 0-A) / h2@0, zz@4352, d1@5632, d2@9984 (B-F)
//   region1 [18432,35072): h1 [32][520] (A-B)
#define XS_OFF 0
#define H2_OFF 0
#define ZZ_OFF 4352
#define D1_OFF 5632
#define D2_OFF 9984
#define H1_OFF 18432
#define SMEM_U16 35072

__global__ __launch_bounds__(NT, 2) void ae_coop(
    const float* __restrict__ x,
    const float* __restrict__ gb,  const float* __restrict__ b1,
    const float* __restrict__ b2,  const float* __restrict__ db1,
    const float* __restrict__ db2, const float* __restrict__ db3,
    const float* __restrict__ gw,  const float* __restrict__ mask,
    const int*   __restrict__ idx,
    const float* __restrict__ w1,  const float* __restrict__ w2,
    const float* __restrict__ dw1, const float* __restrict__ dw2,
    const float* __restrict__ dw3,
    u16* __restrict__ ws,
    float* __restrict__ out, int G, int K)
{
    __shared__ __align__(16) u16 smem[SMEM_U16];
    __shared__ float biases[1568];   // gb512 | b1 128 | b2 32 | db1 128 | db2 256 | db3 512
    u16* xs = smem + XS_OFF;
    u16* h1 = smem + H1_OFF;
    u16* h2 = smem + H2_OFF;
    u16* zz = smem + ZZ_OFF;
    u16* d1 = smem + D1_OFF;
    u16* d2 = smem + D2_OFF;

    const int tid  = threadIdx.x;
    const int wave = tid >> 6;
    const int lane = tid & 63;
    const int b0   = blockIdx.x * TB;
    const int copy = blockIdx.x & 7;              // per-XCD weight copy (heuristic)
    u16* wsb = ws + (size_t)copy * COPY_U16;

    // ---- step 1: build this XCD's weight copy (32 blocks share one copy) ----
    for (int c = (blockIdx.x >> 3) * NT + tid; c < NCHUNK; c += 32 * NT)
        build_chunk(c, wsb, w1, w2, dw1, dw2, dw3, gw, mask, idx, G, K);

    // ---- overlap the sync wait: stage biases + x tile into LDS ----
    biases[tid]        = (tid < GDIM) ? gb[tid] : 0.f;
    biases[1056 + tid] = db3[tid];
    if (tid < 128) biases[512 + tid] = b1[tid];
    if (tid < 32)  biases[640 + tid] = b2[tid];
    if (tid < 128) biases[672 + tid] = db1[tid];
    if (tid < 256) biases[800 + tid] = db2[tid];
    {
        const float4* xg = (const float4*)(x + (size_t)b0 * SAMPLE);
        #pragma unroll
        for (int it = 0; it < (TB * SAMPLE / 4) / NT; ++it) {
            int v = it * NT + tid;             // float4 index
            float4 f = xg[v];
            int row = v >> 7;                  // 128 float4 per row
            int cp  = (v & 127) * 4;
            u16* p = xs + row * 520 + cp;
            u16 t4[4] = { f2b(f.x), f2b(f.y), f2b(f.z), f2b(f.w) };
            *(unsigned long long*)p = *(unsigned long long*)t4;
        }
    }

    // ---- grid-wide barrier: all weight copies complete & visible ----
    cooperative_groups::this_grid().sync();

    // A: h1 = relu(x @ Wg + gb)        [32,512] x [512,512]
    mfma_phase<16, 32, 4>(wave, lane, xs, 520, wsb + WGP_OFF,  biases,       h1, 520);
    __syncthreads();
    // B: h2 = relu(h1 @ w1 + b1)       [32,512] x [512,128]  (h2 overlays dead xs)
    mfma_phase<16, 8, 1>(wave, lane, h1, 520, wsb + W1P_OFF,  biases + 512, h2, 136);
    __syncthreads();

    // C+D fused per-wave: waves 0,1 each own one m-tile (zz same-wave dep)
    if (wave < 2) {
        const int mt = wave;
        {   // C: z = relu(h2 @ w2 + b2)    [16,128] x [128,32]
            const u16* arow = h2 + (mt * 16 + (lane & 15)) * 136 + (lane >> 4) * 8;
            const u16* pW = wsb + W2P_OFF;
            f32x4 acc[2];
            acc[0] = (f32x4){0.f, 0.f, 0.f, 0.f};
            acc[1] = (f32x4){0.f, 0.f, 0.f, 0.f};
            #pragma unroll
            for (int kt = 0; kt < 4; ++kt) {
                s16x8 a = *(const s16x8*)(arow + kt * 32);
                #pragma unroll
                for (int i = 0; i < 2; ++i) {
                    s16x8 b = *(const s16x8*)(pW + (size_t)((i * 4 + kt) * 64 + lane) * 8);
                    acc[i] = __builtin_amdgcn_mfma_f32_16x16x32_bf16(a, b, acc[i], 0, 0, 0);
                }
            }
            #pragma unroll
            for (int i = 0; i < 2; ++i) {
                int col = i * 16 + (lane & 15);
                float bs = biases[640 + col];
                #pragma unroll
                for (int r = 0; r < 4; ++r) {
                    int row = mt * 16 + (lane >> 4) * 4 + r;
                    float v = acc[i][r] + bs;
                    zz[row * 40 + col] = f2b(v > 0.f ? v : 0.f);
                }
            }
        }
        {   // D: d1 = relu(z @ dw1 + db1)  [16,32] x [32,128]
            const u16* arow = zz + (mt * 16 + (lane & 15)) * 40 + (lane >> 4) * 8;
            const u16* pW = wsb + DW1P_OFF;
            s16x8 a = *(const s16x8*)(arow);
            f32x4 acc[8];
            #pragma unroll
            for (int i = 0; i < 8; ++i) {
                s16x8 b = *(const s16x8*)(pW + (size_t)(i * 64 + lane) * 8);
                acc[i] = __builtin_amdgcn_mfma_f32_16x16x32_bf16(
                    a, b, (f32x4){0.f, 0.f, 0.f, 0.f}, 0, 0, 0);
            }
            #pragma unroll
            for (int i = 0; i < 8; ++i) {
                int col = i * 16 + (lane & 15);
                float bs = biases[672 + col];
                #pragma unroll
                for (int r = 0; r < 4; ++r) {
                    int row = mt * 16 + (lane >> 4) * 4 + r;
                    float v = acc[i][r] + bs;
                    d1[row * 136 + col] = f2b(v > 0.f ? v : 0.f);
                }
            }
        }
    }
    __syncthreads();

    // E: d2 = relu(d1 @ dw2 + db2)     [32,128] x [128,256]
    mfma_phase<4, 16, 2>(wave, lane, d1, 136, wsb + DW2P_OFF, biases + 800, d2, 264);
    __syncthreads();

    // F: out = sigmoid(d2 @ dw3 + db3) [32,256] x [256,512] -> global fp32
    {
        const u16* arow0 = d2 + (lane & 15) * 264 + (lane >> 4) * 8;
        const u16* arow1 = arow0 + 16 * 264;
        const u16* pW = wsb + DW3P_OFF;
        f32x4 acc[4][2];
        #pragma unroll
        for (int i = 0; i < 4; ++i) {
            acc[i][0] = (f32x4){0.f, 0.f, 0.f, 0.f};
            acc[i][1] = (f32x4){0.f, 0.f, 0.f, 0.f};
        }
        #pragma unroll
        for (int kt = 0; kt < 8; ++kt) {
            s16x8 a0 = *(const s16x8*)(arow0 + kt * 32);
            s16x8 a1 = *(const s16x8*)(arow1 + kt * 32);
            #pragma unroll
            for (int i = 0; i < 4; ++i) {
                int nt = wave + 8 * i;
                s16x8 b = *(const s16x8*)(pW + (size_t)((nt * 8 + kt) * 64 + lane) * 8);
                acc[i][0] = __builtin_amdgcn_mfma_f32_16x16x32_bf16(a0, b, acc[i][0], 0, 0, 0);
                acc[i][1] = __builtin_amdgcn_mfma_f32_16x16x32_bf16(a1, b, acc[i][1], 0, 0, 0);
            }
        }
        #pragma unroll
        for (int i = 0; i < 4; ++i) {
            int nt = wave + 8 * i;
            int col = nt * 16 + (lane & 15);
            float bs = biases[1056 + col];
            #pragma unroll
            for (int mt = 0; mt < 2; ++mt) {
                #pragma unroll
                for (int r = 0; r < 4; ++r) {
                    int row = mt * 16 + (lane >> 4) * 4 + r;
                    float v = acc[i][mt][r] + bs;
                    out[(size_t)(b0 + row) * SAMPLE + col] = 1.f / (1.f + __expf(-v));
                }
            }
        }
    }
}

extern "C" void kernel_launch(void* const* d_in, const int* in_sizes, int n_in,
                              void* d_out, int out_size, void* d_ws, size_t ws_size,
                              hipStream_t stream) {
    const float* x   = (const float*)d_in[0];
    const float* gw  = (const float*)d_in[1];
    const float* gb  = (const float*)d_in[2];
    const float* w1  = (const float*)d_in[3];
    const float* b1  = (const float*)d_in[4];
    const float* w2  = (const float*)d_in[5];
    const float* b2  = (const float*)d_in[6];
    const float* dw1 = (const float*)d_in[7];
    const float* db1 = (const float*)d_in[8];
    const float* dw2 = (const float*)d_in[9];
    const float* db2 = (const float*)d_in[10];
    const float* dw3 = (const float*)d_in[11];
    const float* db3 = (const float*)d_in[12];
    const int* idx   = (const int*)d_in[13];
    const float* mask= (const float*)d_in[14];
    float* out = (float*)d_out;
    u16* ws = (u16*)d_ws;

    const int B = in_sizes[0] / SAMPLE;      // 8192
    int G = in_sizes[2];                     // 510
    int K = in_sizes[1] / G;                 // 28

    void* args[] = {
        (void*)&x, (void*)&gb, (void*)&b1, (void*)&b2, (void*)&db1,
        (void*)&db2, (void*)&db3, (void*)&gw, (void*)&mask, (void*)&idx,
        (void*)&w1, (void*)&w2, (void*)&dw1, (void*)&dw2, (void*)&dw3,
        (void*)&ws, (void*)&out, (void*)&G, (void*)&K
    };
    hipLaunchCooperativeKernel((const void*)ae_coop, dim3(B / TB), dim3(NT),
                               args, 0, stream);
}

// Round 14
// 153.597 us; speedup vs baseline: 1.2612x; 1.2612x over previous
//
#include <hip/hip_runtime.h>
#include <hip/hip_bf16.h>

#define SAMPLE 512
#define GDIM   510
#define HID    128
#define LATENT 32
#define HID2   256
#define BATCH  8192

typedef unsigned short u16;
typedef unsigned int   u32;
typedef __attribute__((ext_vector_type(8))) short s16x8;
typedef __attribute__((ext_vector_type(4))) float f32x4;

// packed-weight layout per matrix: [nt][kt][lane 0..63][j 0..7] (16B chunks)
#define WGP_OFF   0                         // gather W: N=512(510) K=512
#define W1P_OFF   (WGP_OFF  + 32*16*512)    // w1:  N=128 K=512(510)
#define W2P_OFF   (W1P_OFF  + 8*16*512)     // w2:  N=32  K=128
#define DW1P_OFF  (W2P_OFF  + 2*4*512)      // dw1: N=128 K=32
#define DW2P_OFF  (DW1P_OFF + 8*1*512)      // dw2: N=256 K=128
#define DW3P_OFF  (DW2P_OFF + 16*4*512)     // dw3: N=512 K=256
#define PACK_U16  (DW3P_OFF + 32*8*512)     // 499712
#define NCHUNK    (PACK_U16 / 8)            // 62464

// activation buffers in d_ws (u16 offsets), all row-major bf16
#define XB_OFF  524288
#define H1_OFF  (XB_OFF + BATCH*SAMPLE)     // 4718592
#define H2_OFF  (H1_OFF + BATCH*SAMPLE)     // 8912896
#define ZZ_OFF  (H2_OFF + BATCH*HID)        // 9961472
#define D1_OFF  (ZZ_OFF + BATCH*LATENT)     // 10223616
#define D2_OFF  (D1_OFF + BATCH*HID)        // 11272192

#define XCONV   (BATCH*SAMPLE/8)            // 524288 8-elem conversion chunks

__device__ __forceinline__ u16 f2b(float f) {
    union { float f; u32 i; } v; v.f = f;
    return (u16)((v.i + 0x7FFFu + ((v.i >> 16) & 1u)) >> 16);
}

// ---------------- pack kernel: weights -> packed bf16, x -> bf16 ----------------
__global__ __launch_bounds__(256) void pack_all(
    const float* __restrict__ x,
    const float* __restrict__ w1, const float* __restrict__ w2,
    const float* __restrict__ dw1, const float* __restrict__ dw2,
    const float* __restrict__ dw3,
    const float* __restrict__ gw, const float* __restrict__ mask,
    const int* __restrict__ idx,
    u16* __restrict__ ws, int G, int K)
{
    int c = blockIdx.x * 256 + threadIdx.x;
    if (c >= NCHUNK + XCONV) return;
    u16 tmp[8];
    if (c >= NCHUNK) {                     // x -> bf16 conversion
        int cx = c - NCHUNK;
        const float4* xp = (const float4*)(x + (size_t)cx * 8);
        float4 f0 = xp[0], f1 = xp[1];
        tmp[0]=f2b(f0.x); tmp[1]=f2b(f0.y); tmp[2]=f2b(f0.z); tmp[3]=f2b(f0.w);
        tmp[4]=f2b(f1.x); tmp[5]=f2b(f1.y); tmp[6]=f2b(f1.z); tmp[7]=f2b(f1.w);
        *(s16x8*)(ws + XB_OFF + (size_t)cx * 8) = *(s16x8*)tmp;
        return;
    }
    if (c < W1P_OFF / 8) {                 // gather-W region
        int lane = c & 63;
        int kt   = (c >> 6) & 15;
        int nt   = (c >> 6) >> 4;
        int g    = nt * 16 + (lane & 15);
        int k0   = kt * 32 + (lane >> 4) * 8;
        #pragma unroll
        for (int j = 0; j < 8; ++j) tmp[j] = 0;
        if (g < G) {
            const int*   idxr = idx  + (size_t)g * K;
            const float* gwr  = gw   + (size_t)g * K;
            const float* mr   = mask + (size_t)g * K;
            for (int t = 0; t < K; ++t) {
                int j = idxr[t] - k0;
                float m = mr[t];
                if ((unsigned)j < 8u && m > 0.f) tmp[j] = f2b(gwr[t] * m);
            }
        }
        *(s16x8*)(ws + (size_t)c * 8) = *(s16x8*)tmp;
        return;
    }
    const float* W; int Kd, Nd, KT, base;
    if      (c < W2P_OFF / 8)  { W = w1;  Kd = GDIM;   Nd = HID;    KT = 16; base = W1P_OFF / 8; }
    else if (c < DW1P_OFF / 8) { W = w2;  Kd = HID;    Nd = LATENT; KT = 4;  base = W2P_OFF / 8; }
    else if (c < DW2P_OFF / 8) { W = dw1; Kd = LATENT; Nd = HID;    KT = 1;  base = DW1P_OFF / 8; }
    else if (c < DW3P_OFF / 8) { W = dw2; Kd = HID;    Nd = HID2;   KT = 4;  base = DW2P_OFF / 8; }
    else                       { W = dw3; Kd = HID2;   Nd = SAMPLE; KT = 8;  base = DW3P_OFF / 8; }
    int c2   = c - base;
    int lane = c2 & 63;
    int kt   = (c2 >> 6) % KT;
    int nt   = (c2 >> 6) / KT;
    int n    = nt * 16 + (lane & 15);
    int k0   = kt * 32 + (lane >> 4) * 8;
    #pragma unroll
    for (int j = 0; j < 8; ++j) {
        int k = k0 + j;
        float v = (k < Kd && n < Nd) ? W[(size_t)k * Nd + n] : 0.f;
        tmp[j] = f2b(v);
    }
    *(s16x8*)(ws + (size_t)c * 8) = *(s16x8*)tmp;
}

// ---------------- generic phase GEMM: weights + input tile in LDS ----------------
// out[TBR=64 rows x NSLICE=NS16*16 cols] per block. NT=512, 8 waves.
// Wave w: m-tile = w&3 (4 m-tiles), n-tiles ng0..ng0+NPW-1 where ng0=(w>>2)*NPW.
// K-loop is ALL-LDS: zero global loads on the critical path.
template<int KT, int NS16, int OUT_SIG>
__global__ __launch_bounds__(512) void gemm_phase(
    const u16* __restrict__ ws_ro, u16* __restrict__ ws_wr,
    const float* __restrict__ bias, int bias_n,
    float* __restrict__ fout,
    int in_off, int w_off, int out_off, int n_total, int nsl)
{
    constexpr int KTOT  = KT * 32;
    constexpr int SIN   = KTOT + 8;          // padded LDS row stride
    constexpr int TBR   = 64;
    constexpr int WSPAN = NS16 * KT * 512;   // u16 per W slice
    constexpr int NPW   = NS16 / 2;          // n-tiles per wave
    __shared__ __align__(16) u16 wt[WSPAN];
    __shared__ __align__(16) u16 xt[TBR * SIN];

    const int tid  = threadIdx.x;
    const int wave = tid >> 6;
    const int lane = tid & 63;
    const int rt   = blockIdx.x / nsl;
    const int ns   = blockIdx.x % nsl;

    // stage W slice (contiguous span of packed layout, coalesced 16B/lane)
    {
        const u16* src = ws_ro + w_off + (size_t)ns * WSPAN;
        for (int off = tid * 8; off < WSPAN; off += 512 * 8)
            *(s16x8*)(wt + off) = *(const s16x8*)(src + off);
    }
    // stage input tile (contiguous rows -> padded LDS rows, coalesced)
    {
        const u16* src = ws_ro + in_off + (size_t)rt * TBR * KTOT;
        for (int off = tid * 8; off < TBR * KTOT; off += 512 * 8) {
            int row = off / KTOT;            // KTOT is pow2 -> shift
            int col = off - row * KTOT;
            *(s16x8*)(xt + row * SIN + col) = *(const s16x8*)(src + off);
        }
    }
    __syncthreads();

    const int m   = wave & 3;
    const int ng0 = (wave >> 2) * NPW;
    const u16* arow = xt + (m * 16 + (lane & 15)) * SIN + (lane >> 4) * 8;
    f32x4 acc[NPW];
    #pragma unroll
    for (int i = 0; i < NPW; ++i) acc[i] = (f32x4){0.f, 0.f, 0.f, 0.f};
    #pragma unroll
    for (int kt = 0; kt < KT; ++kt) {
        s16x8 a = *(const s16x8*)(arow + kt * 32);
        #pragma unroll
        for (int i = 0; i < NPW; ++i) {
            int nt = ng0 + i;
            s16x8 b = *(const s16x8*)(wt + ((nt * KT + kt) * 64 + lane) * 8);
            acc[i] = __builtin_amdgcn_mfma_f32_16x16x32_bf16(a, b, acc[i], 0, 0, 0);
        }
    }
    // epilogue: bias + activation + store
    #pragma unroll
    for (int i = 0; i < NPW; ++i) {
        int nt   = ng0 + i;
        int colg = ns * (NS16 * 16) + nt * 16 + (lane & 15);
        float bs = (colg < bias_n) ? bias[colg] : 0.f;
        #pragma unroll
        for (int r = 0; r < 4; ++r) {
            int rowg = rt * TBR + m * 16 + (lane >> 4) * 4 + r;
            float v = acc[i][r] + bs;
            if (OUT_SIG) {
                fout[(size_t)rowg * n_total + colg] = 1.f / (1.f + __expf(-v));
            } else {
                v = v > 0.f ? v : 0.f;
                ws_wr[out_off + (size_t)rowg * n_total + colg] = f2b(v);
            }
        }
    }
}

extern "C" void kernel_launch(void* const* d_in, const int* in_sizes, int n_in,
                              void* d_out, int out_size, void* d_ws, size_t ws_size,
                              hipStream_t stream) {
    const float* x   = (const float*)d_in[0];
    const float* gw  = (const float*)d_in[1];
    const float* gb  = (const float*)d_in[2];
    const float* w1  = (const float*)d_in[3];
    const float* b1  = (const float*)d_in[4];
    const float* w2  = (const float*)d_in[5];
    const float* b2  = (const float*)d_in[6];
    const float* dw1 = (const float*)d_in[7];
    const float* db1 = (const float*)d_in[8];
    const float* dw2 = (const float*)d_in[9];
    const float* db2 = (const float*)d_in[10];
    const float* dw3 = (const float*)d_in[11];
    const float* db3 = (const float*)d_in[12];
    const int* idx   = (const int*)d_in[13];
    const float* mask= (const float*)d_in[14];
    float* out = (float*)d_out;
    u16* ws = (u16*)d_ws;

    const int G = in_sizes[2];               // 510
    const int K = in_sizes[1] / G;           // 28

    // pack weights + convert x to bf16
    pack_all<<<(NCHUNK + XCONV + 255) / 256, 256, 0, stream>>>(
        x, w1, w2, dw1, dw2, dw3, gw, mask, idx, ws, G, K);

    // A: h1 = relu(xb @ Wg + gb)    [8192,512]x[512,512]  grid 128x8
    gemm_phase<16, 4, 0><<<1024, 512, 0, stream>>>(
        ws, ws, gb, GDIM, out, XB_OFF, WGP_OFF, H1_OFF, SAMPLE, 8);
    // B: h2 = relu(h1 @ w1 + b1)    [8192,512]x[512,128]  grid 128x2
    gemm_phase<16, 4, 0><<<256, 512, 0, stream>>>(
        ws, ws, b1, HID, out, H1_OFF, W1P_OFF, H2_OFF, HID, 2);
    // C: z = relu(h2 @ w2 + b2)     [8192,128]x[128,32]   grid 128x1
    gemm_phase<4, 2, 0><<<128, 512, 0, stream>>>(
        ws, ws, b2, LATENT, out, H2_OFF, W2P_OFF, ZZ_OFF, LATENT, 1);
    // D: d1 = relu(z @ dw1 + db1)   [8192,32]x[32,128]    grid 128x1
    gemm_phase<1, 8, 0><<<128, 512, 0, stream>>>(
        ws, ws, db1, HID, out, ZZ_OFF, DW1P_OFF, D1_OFF, HID, 1);
    // E: d2 = relu(d1 @ dw2 + db2)  [8192,128]x[128,256]  grid 128x2
    gemm_phase<4, 8, 0><<<256, 512, 0, stream>>>(
        ws, ws, db2, HID2, out, D1_OFF, DW2P_OFF, D2_OFF, HID2, 2);
    // F: out = sigmoid(d2 @ dw3 + db3) [8192,256]x[256,512] grid 128x8, fp32 out
    gemm_phase<8, 4, 1><<<1024, 512, 0, stream>>>(
        ws, ws, db3, SAMPLE, out, D2_OFF, DW3P_OFF, 0, SAMPLE, 8);
}

// Round 15
// 138.531 us; speedup vs baseline: 1.3983x; 1.1088x over previous
//
#include <hip/hip_runtime.h>
#include <hip/hip_bf16.h>

#define SAMPLE 512
#define GDIM   510
#define HID    128
#define LATENT 32
#define HID2   256
#define TB     32      // batch rows per block = two 16-row m-tiles
#define NT     512     // 8 waves

typedef unsigned short u16;
typedef unsigned int   u32;
typedef __attribute__((ext_vector_type(8))) short s16x8;
typedef __attribute__((ext_vector_type(4))) float f32x4;

// packed-weight regions in d_ws (u16 element offsets)
// layout per matrix: [nt][kt][lane 0..63][j 0..7], chunk = 8 u16 = 16 B
#define WGP_OFF   0                         // gather W: N=512(510) K=512
#define W1P_OFF   (WGP_OFF  + 32*16*512)    // w1:  N=128 K=512(510)
#define W2P_OFF   (W1P_OFF  + 8*16*512)     // w2:  N=32  K=128
#define DW1P_OFF  (W2P_OFF  + 2*4*512)      // dw1: N=128 K=32
#define DW2P_OFF  (DW1P_OFF + 8*1*512)      // dw2: N=256 K=128
#define DW3P_OFF  (DW2P_OFF + 16*4*512)     // dw3: N=512 K=256
#define PACK_U16  (DW3P_OFF + 32*8*512)
#define NCHUNK    (PACK_U16 / 8)

__device__ __forceinline__ u16 f2b(float f) {
    union { float f; u32 i; } v; v.f = f;
    return (u16)((v.i + 0x7FFFu + ((v.i >> 16) & 1u)) >> 16);
}

// ---------------- prologue: build all packed weights (single copy) ----------------
__global__ __launch_bounds__(256) void build_ws(
    const float* __restrict__ w1, const float* __restrict__ w2,
    const float* __restrict__ dw1, const float* __restrict__ dw2,
    const float* __restrict__ dw3,
    const float* __restrict__ gw, const float* __restrict__ mask,
    const int* __restrict__ idx,
    u16* __restrict__ ws, int G, int K)
{
    int c = blockIdx.x * 256 + threadIdx.x;
    if (c >= NCHUNK) return;
    u16 tmp[8];
    if (c < W1P_OFF / 8) {                 // gather-W region
        int lane = c & 63;
        int kt   = (c >> 6) & 15;
        int nt   = (c >> 6) >> 4;
        int g    = nt * 16 + (lane & 15);
        int k0   = kt * 32 + (lane >> 4) * 8;
        #pragma unroll
        for (int j = 0; j < 8; ++j) tmp[j] = 0;
        if (g < G) {
            const int*   idxr = idx  + (size_t)g * K;
            const float* gwr  = gw   + (size_t)g * K;
            const float* mr   = mask + (size_t)g * K;
            int t = 0;
            for (; t + 4 <= K; t += 4) {
                int   j0 = idxr[t]     - k0, j1 = idxr[t + 1] - k0;
                int   j2 = idxr[t + 2] - k0, j3 = idxr[t + 3] - k0;
                float m0 = mr[t],     m1 = mr[t + 1];
                float m2 = mr[t + 2], m3 = mr[t + 3];
                float v0 = gwr[t],     v1 = gwr[t + 1];
                float v2 = gwr[t + 2], v3 = gwr[t + 3];
                if ((unsigned)j0 < 8u && m0 > 0.f) tmp[j0] = f2b(v0 * m0);
                if ((unsigned)j1 < 8u && m1 > 0.f) tmp[j1] = f2b(v1 * m1);
                if ((unsigned)j2 < 8u && m2 > 0.f) tmp[j2] = f2b(v2 * m2);
                if ((unsigned)j3 < 8u && m3 > 0.f) tmp[j3] = f2b(v3 * m3);
            }
            for (; t < K; ++t) {
                int j = idxr[t] - k0;
                float m = mr[t];
                if ((unsigned)j < 8u && m > 0.f) tmp[j] = f2b(gwr[t] * m);
            }
        }
        *(s16x8*)(ws + (size_t)c * 8) = *(s16x8*)tmp;
        return;
    }
    const float* W; int Kd, Nd, KT, base;
    if      (c < W2P_OFF / 8)  { W = w1;  Kd = GDIM;   Nd = HID;    KT = 16; base = W1P_OFF / 8; }
    else if (c < DW1P_OFF / 8) { W = w2;  Kd = HID;    Nd = LATENT; KT = 4;  base = W2P_OFF / 8; }
    else if (c < DW2P_OFF / 8) { W = dw1; Kd = LATENT; Nd = HID;    KT = 1;  base = DW1P_OFF / 8; }
    else if (c < DW3P_OFF / 8) { W = dw2; Kd = HID;    Nd = HID2;   KT = 4;  base = DW2P_OFF / 8; }
    else                       { W = dw3; Kd = HID2;   Nd = SAMPLE; KT = 8;  base = DW3P_OFF / 8; }
    int c2   = c - base;
    int lane = c2 & 63;
    int kt   = (c2 >> 6) % KT;
    int nt   = (c2 >> 6) / KT;
    int n    = nt * 16 + (lane & 15);
    int k0   = kt * 32 + (lane >> 4) * 8;
    #pragma unroll
    for (int j = 0; j < 8; ++j) {
        int k = k0 + j;
        float v = (k < Kd && n < Nd) ? W[(size_t)k * Nd + n] : 0.f;
        tmp[j] = f2b(v);
    }
    *(s16x8*)(ws + (size_t)c * 8) = *(s16x8*)tmp;
}

// ---------------- chunked MFMA phase: B staged in LDS (bulk, cooperative) ----------------
// N = NTN*16 split into chunks of CN n-tiles. All 512 threads stage the chunk's
// packed W slice (coalesced 16B/lane), barrier, then wave w (w < 2*CN) computes
// (nt_l = w%CN, mt = (w/CN)&1) via a pure-LDS K-loop. 2 barriers/chunk.
// SIG=1: sigmoid epilogue to global fp32 (fout, row base b0).
template<int KT, int NTN, int CN, int SIG>
__device__ __forceinline__ void mfma_phase_c(
    int tid, int wave, int lane,
    const u16* inl, int sin,
    const u16* __restrict__ pW, u16* wbuf,
    const float* bias,
    u16* outl, int sout,
    float* fout, int b0)
{
    constexpr int NCH = NTN / CN;
    constexpr int CHU = CN * KT * 512;        // u16 per chunk
    const int nt_l = wave % CN;
    const int mt   = (wave / CN) & 1;
    const bool act = wave < 2 * CN;
    const u16* arow = inl + (mt * 16 + (lane & 15)) * sin + (lane >> 4) * 8;

    for (int c = 0; c < NCH; ++c) {
        // bulk stage chunk c (512 thr x 16B sweeps)
        {
            const u16* src = pW + (size_t)c * CHU;
            for (int off = tid * 8; off < CHU; off += NT * 8)
                *(s16x8*)(wbuf + off) = *(const s16x8*)(src + off);
        }
        __syncthreads();
        if (act) {
            f32x4 acc = (f32x4){0.f, 0.f, 0.f, 0.f};
            #pragma unroll
            for (int kt = 0; kt < KT; ++kt) {
                s16x8 a = *(const s16x8*)(arow + kt * 32);
                s16x8 b = *(const s16x8*)(wbuf + ((nt_l * KT + kt) * 64 + lane) * 8);
                acc = __builtin_amdgcn_mfma_f32_16x16x32_bf16(a, b, acc, 0, 0, 0);
            }
            int nt  = c * CN + nt_l;
            int col = nt * 16 + (lane & 15);
            float bs = bias[col];
            #pragma unroll
            for (int r = 0; r < 4; ++r) {
                int row = mt * 16 + (lane >> 4) * 4 + r;
                float v = acc[r] + bs;
                if (SIG) {
                    fout[(size_t)(b0 + row) * SAMPLE + col] = 1.f / (1.f + __expf(-v));
                } else {
                    outl[row * sout + col] = f2b(v > 0.f ? v : 0.f);
                }
            }
        }
        __syncthreads();    // wbuf safe to overwrite
    }
}

// ---------------- fused main kernel ----------------
// LDS: acts overlay 70.1 KB + wbuf 64 KB + biases 6.1 KB = 139 KB (1 block/CU)
#define XS_OFF 0
#define H2_OFF 0
#define ZZ_OFF 4352
#define D1_OFF 5632
#define D2_OFF 9984
#define H1_OFF 18432
#define SMEM_U16 35072
#define WBUF_U16 32768

__global__ __launch_bounds__(NT, 2) void ae_mfma(
    const float* __restrict__ x,
    const float* __restrict__ gb,  const float* __restrict__ b1,
    const float* __restrict__ b2,  const float* __restrict__ db1,
    const float* __restrict__ db2, const float* __restrict__ db3,
    const u16*   __restrict__ ws,
    float* __restrict__ out)
{
    __shared__ __align__(16) u16 smem[SMEM_U16];
    __shared__ __align__(16) u16 wbuf[WBUF_U16];
    __shared__ float biases[1568];   // gb512 | b1 128 | b2 32 | db1 128 | db2 256 | db3 512
    u16* xs = smem + XS_OFF;
    u16* h1 = smem + H1_OFF;
    u16* h2 = smem + H2_OFF;
    u16* zz = smem + ZZ_OFF;
    u16* d1 = smem + D1_OFF;
    u16* d2 = smem + D2_OFF;

    const int tid  = threadIdx.x;
    const int wave = tid >> 6;
    const int lane = tid & 63;
    const int b0   = blockIdx.x * TB;

    // stage biases (gb zero-padded to 512)
    biases[tid]        = (tid < GDIM) ? gb[tid] : 0.f;
    biases[1056 + tid] = db3[tid];
    if (tid < 128) biases[512 + tid] = b1[tid];
    if (tid < 32)  biases[640 + tid] = b2[tid];
    if (tid < 128) biases[672 + tid] = db1[tid];
    if (tid < 256) biases[800 + tid] = db2[tid];

    // stage x tile -> bf16 LDS
    {
        const float4* xg = (const float4*)(x + (size_t)b0 * SAMPLE);
        #pragma unroll
        for (int it = 0; it < (TB * SAMPLE / 4) / NT; ++it) {
            int v = it * NT + tid;             // float4 index
            float4 f = xg[v];
            int row = v >> 7;                  // 128 float4 per row
            int cp  = (v & 127) * 4;
            u16* p = xs + row * 520 + cp;
            u16 t4[4] = { f2b(f.x), f2b(f.y), f2b(f.z), f2b(f.w) };
            *(unsigned long long*)p = *(unsigned long long*)t4;
        }
    }
    // NOTE: first chunk barrier inside phase A covers xs/bias visibility.

    // A: h1 = relu(x @ Wg + gb)        [32,512] x [512,512]
    mfma_phase_c<16, 32, 4, 0>(tid, wave, lane, xs, 520, ws + WGP_OFF, wbuf,
                               biases,       h1, 520, out, b0);
    // B: h2 = relu(h1 @ w1 + b1)      [32,512] x [512,128]
    mfma_phase_c<16, 8, 4, 0>(tid, wave, lane, h1, 520, ws + W1P_OFF, wbuf,
                              biases + 512, h2, 136, out, b0);
    // C: z = relu(h2 @ w2 + b2)       [32,128] x [128,32]
    mfma_phase_c<4, 2, 2, 0>(tid, wave, lane, h2, 136, ws + W2P_OFF, wbuf,
                             biases + 640, zz, 40, out, b0);
    // D: d1 = relu(z @ dw1 + db1)     [32,32] x [32,128]
    mfma_phase_c<1, 8, 4, 0>(tid, wave, lane, zz, 40, ws + DW1P_OFF, wbuf,
                             biases + 672, d1, 136, out, b0);
    // E: d2 = relu(d1 @ dw2 + db2)    [32,128] x [128,256]
    mfma_phase_c<4, 16, 4, 0>(tid, wave, lane, d1, 136, ws + DW2P_OFF, wbuf,
                              biases + 800, d2, 264, out, b0);
    // F: out = sigmoid(d2 @ dw3 + db3) [32,256] x [256,512] -> global fp32
    mfma_phase_c<8, 32, 4, 1>(tid, wave, lane, d2, 264, ws + DW3P_OFF, wbuf,
                              biases + 1056, (u16*)nullptr, 0, out, b0);
}

extern "C" void kernel_launch(void* const* d_in, const int* in_sizes, int n_in,
                              void* d_out, int out_size, void* d_ws, size_t ws_size,
                              hipStream_t stream) {
    const float* x   = (const float*)d_in[0];
    const float* gw  = (const float*)d_in[1];
    const float* gb  = (const float*)d_in[2];
    const float* w1  = (const float*)d_in[3];
    const float* b1  = (const float*)d_in[4];
    const float* w2  = (const float*)d_in[5];
    const float* b2  = (const float*)d_in[6];
    const float* dw1 = (const float*)d_in[7];
    const float* db1 = (const float*)d_in[8];
    const float* dw2 = (const float*)d_in[9];
    const float* db2 = (const float*)d_in[10];
    const float* dw3 = (const float*)d_in[11];
    const float* db3 = (const float*)d_in[12];
    const int* idx   = (const int*)d_in[13];
    const float* mask= (const float*)d_in[14];
    float* out = (float*)d_out;
    u16* ws = (u16*)d_ws;

    const int B  = in_sizes[0] / SAMPLE;     // 8192
    const int G  = in_sizes[2];              // 510
    const int K  = in_sizes[1] / G;          // 28

    build_ws<<<(NCHUNK + 255) / 256, 256, 0, stream>>>(w1, w2, dw1, dw2, dw3,
                                                       gw, mask, idx, ws, G, K);
    ae_mfma<<<B / TB, NT, 0, stream>>>(x, gb, b1, b2, db1, db2, db3, ws, out);
}

// Round 16
// 125.395 us; speedup vs baseline: 1.5448x; 1.1048x over previous
//
#include <hip/hip_runtime.h>
#include <hip/hip_bf16.h>

#define SAMPLE 512
#define GDIM   510
#define HID    128
#define LATENT 32
#define HID2   256
#define TB     16      // batch rows per block = one 16-row m-tile
#define NT     512     // 8 waves

typedef unsigned short u16;
typedef unsigned int   u32;
typedef __attribute__((ext_vector_type(8))) short s16x8;
typedef __attribute__((ext_vector_type(4))) float f32x4;

// packed-weight regions in d_ws (u16 element offsets)
// layout per matrix: [nt][kt][lane 0..63][j 0..7], chunk = 8 u16 = 16 B
#define WGP_OFF   0                         // gather W: N=512(510) K=512
#define W1P_OFF   (WGP_OFF  + 32*16*512)    // w1:  N=128 K=512(510)
#define W2P_OFF   (W1P_OFF  + 8*16*512)     // w2:  N=32  K=128
#define DW1P_OFF  (W2P_OFF  + 2*4*512)      // dw1: N=128 K=32
#define DW2P_OFF  (DW1P_OFF + 8*1*512)      // dw2: N=256 K=128
#define DW3P_OFF  (DW2P_OFF + 16*4*512)     // dw3: N=512 K=256
#define PACK_U16  (DW3P_OFF + 32*8*512)
#define NCHUNK    (PACK_U16 / 8)
#define BW_NTH    (512 * 256)               // build_ws total threads

__device__ __forceinline__ u16 f2b(float f) {
    union { float f; u32 i; } v; v.f = f;
    return (u16)((v.i + 0x7FFFu + ((v.i >> 16) & 1u)) >> 16);
}

// ---------------- prologue: L2-warm inputs, then build packed weights ----------------
__global__ __launch_bounds__(256) void build_ws(
    const float* __restrict__ w1, const float* __restrict__ w2,
    const float* __restrict__ dw1, const float* __restrict__ dw2,
    const float* __restrict__ dw3,
    const float* __restrict__ gw, const float* __restrict__ mask,
    const int* __restrict__ idx,
    u16* __restrict__ ws, int G, int K)
{
    int t = blockIdx.x * 256 + threadIdx.x;

    // ---- pass 1: coalesced L2 warm of everything the scattered pass reads ----
    float wa = 0.f;
    {
        const int gk4 = (G * K) / 4;
        if (t < gk4) {
            float4 a = ((const float4*)gw)[t];
            float4 b = ((const float4*)mask)[t];
            float4 c = ((const float4*)idx)[t];   // bytes only; value unused
            wa += a.x + b.x + c.x;
        }
        #define WARM(P, NF) { int n4 = (NF) / 4; \
            for (int i = t; i < n4; i += BW_NTH) { float4 a = ((const float4*)(P))[i]; wa += a.x + a.w; } }
        WARM(w1,  GDIM * HID)
        WARM(w2,  HID * LATENT)
        WARM(dw1, LATENT * HID)
        WARM(dw2, HID * HID2)
        WARM(dw3, HID2 * SAMPLE)
        #undef WARM
        if (wa == 123456789.0f) ws[PACK_U16 + (t & 1023)] = 1;  // never true; defeats DCE
    }

    // ---- pass 2: one thread per 16-B chunk ----
    int c = t;
    if (c >= NCHUNK) return;
    u16 tmp[8];
    if (c < W1P_OFF / 8) {                 // gather-W region (scan group's K triples)
        int lane = c & 63;
        int kt   = (c >> 6) & 15;
        int nt   = (c >> 6) >> 4;
        int g    = nt * 16 + (lane & 15);
        int k0   = kt * 32 + (lane >> 4) * 8;
        #pragma unroll
        for (int j = 0; j < 8; ++j) tmp[j] = 0;
        if (g < G) {
            const int*   idxr = idx  + (size_t)g * K;
            const float* gwr  = gw   + (size_t)g * K;
            const float* mr   = mask + (size_t)g * K;
            int tt = 0;
            for (; tt + 4 <= K; tt += 4) {
                int   j0 = idxr[tt]     - k0, j1 = idxr[tt + 1] - k0;
                int   j2 = idxr[tt + 2] - k0, j3 = idxr[tt + 3] - k0;
                float m0 = mr[tt],     m1 = mr[tt + 1];
                float m2 = mr[tt + 2], m3 = mr[tt + 3];
                float v0 = gwr[tt],     v1 = gwr[tt + 1];
                float v2 = gwr[tt + 2], v3 = gwr[tt + 3];
                if ((unsigned)j0 < 8u && m0 > 0.f) tmp[j0] = f2b(v0 * m0);
                if ((unsigned)j1 < 8u && m1 > 0.f) tmp[j1] = f2b(v1 * m1);
                if ((unsigned)j2 < 8u && m2 > 0.f) tmp[j2] = f2b(v2 * m2);
                if ((unsigned)j3 < 8u && m3 > 0.f) tmp[j3] = f2b(v3 * m3);
            }
            for (; tt < K; ++tt) {
                int j = idxr[tt] - k0;
                float m = mr[tt];
                if ((unsigned)j < 8u && m > 0.f) tmp[j] = f2b(gwr[tt] * m);
            }
        }
        *(s16x8*)(ws + (size_t)c * 8) = *(s16x8*)tmp;
        return;
    }
    const float* W; int Kd, Nd, KT, base;
    if      (c < W2P_OFF / 8)  { W = w1;  Kd = GDIM;   Nd = HID;    KT = 16; base = W1P_OFF / 8; }
    else if (c < DW1P_OFF / 8) { W = w2;  Kd = HID;    Nd = LATENT; KT = 4;  base = W2P_OFF / 8; }
    else if (c < DW2P_OFF / 8) { W = dw1; Kd = LATENT; Nd = HID;    KT = 1;  base = DW1P_OFF / 8; }
    else if (c < DW3P_OFF / 8) { W = dw2; Kd = HID;    Nd = HID2;   KT = 4;  base = DW2P_OFF / 8; }
    else                       { W = dw3; Kd = HID2;   Nd = SAMPLE; KT = 8;  base = DW3P_OFF / 8; }
    int c2   = c - base;
    int lane = c2 & 63;
    int kt   = (c2 >> 6) % KT;
    int nt   = (c2 >> 6) / KT;
    int n    = nt * 16 + (lane & 15);
    int k0   = kt * 32 + (lane >> 4) * 8;
    #pragma unroll
    for (int j = 0; j < 8; ++j) {
        int k = k0 + j;
        float v = (k < Kd && n < Nd) ? W[(size_t)k * Nd + n] : 0.f;
        tmp[j] = f2b(v);
    }
    *(s16x8*)(ws + (size_t)c * 8) = *(s16x8*)tmp;
}

// ---------------- generic MFMA phase: M=16, global-B K-loop ----------------
// N = NTN*16, K = KT*32. 8 waves; wave w owns n-tiles w + 8*i (i<TPW).
template<int KT, int NTN, int TPW>
__device__ __forceinline__ void mfma_phase(
    int wave, int lane,
    const u16* inl, int sin,
    const u16* __restrict__ pW,
    const float* bias,
    u16* outl, int sout)
{
    if (NTN < 8 && wave >= NTN) return;
    const u16* arow = inl + (lane & 15) * sin + (lane >> 4) * 8;
    f32x4 acc[TPW];
    #pragma unroll
    for (int i = 0; i < TPW; ++i) acc[i] = (f32x4){0.f, 0.f, 0.f, 0.f};
    #pragma unroll
    for (int kt = 0; kt < KT; ++kt) {
        s16x8 a = *(const s16x8*)(arow + kt * 32);
        #pragma unroll
        for (int i = 0; i < TPW; ++i) {
            int nt = wave + 8 * i;
            s16x8 b = *(const s16x8*)(pW + (size_t)((nt * KT + kt) * 64 + lane) * 8);
            acc[i] = __builtin_amdgcn_mfma_f32_16x16x32_bf16(a, b, acc[i], 0, 0, 0);
        }
    }
    #pragma unroll
    for (int i = 0; i < TPW; ++i) {
        int nt = wave + 8 * i;
        int col = nt * 16 + (lane & 15);
        float bs = bias[col];
        #pragma unroll
        for (int r = 0; r < 4; ++r) {
            int row = (lane >> 4) * 4 + r;
            float v = acc[i][r] + bs;
            outl[row * sout + col] = f2b(v > 0.f ? v : 0.f);
        }
    }
}

// ---------------- fused main kernel (TB=16, 2 blocks/CU for barrier overlap) ----------------
// LDS union overlay (u16 offsets), TB=16 rows:
//   region0 [0,9216): xs [16][520] (phases 0-A) / h2@0 [16][136], zz@2176 [16][40],
//                     d1@2816 [16][136], d2@5120 [16][264] (phases B-F)
//   region1 [9216,17536): h1 [16][520] (phases A-B)
#define XS_OFF 0
#define H2_OFF 0
#define ZZ_OFF 2176
#define D1_OFF 2816
#define D2_OFF 5120
#define H1_OFF 9216
#define SMEM_U16 17536

__global__ __launch_bounds__(NT, 4) void ae_mfma(
    const float* __restrict__ x,
    const float* __restrict__ gb,  const float* __restrict__ b1,
    const float* __restrict__ b2,  const float* __restrict__ db1,
    const float* __restrict__ db2, const float* __restrict__ db3,
    const u16*   __restrict__ ws,
    float* __restrict__ out)
{
    __shared__ __align__(16) u16 smem[SMEM_U16];
    __shared__ float biases[1568];   // gb512 | b1 128 | b2 32 | db1 128 | db2 256 | db3 512
    u16* xs = smem + XS_OFF;
    u16* h1 = smem + H1_OFF;
    u16* h2 = smem + H2_OFF;
    u16* zz = smem + ZZ_OFF;
    u16* d1 = smem + D1_OFF;
    u16* d2 = smem + D2_OFF;

    const int tid  = threadIdx.x;
    const int wave = tid >> 6;
    const int lane = tid & 63;
    const int b0   = blockIdx.x * TB;

    // stage biases (gb zero-padded to 512)
    biases[tid]        = (tid < GDIM) ? gb[tid] : 0.f;
    biases[1056 + tid] = db3[tid];
    if (tid < 128) biases[512 + tid] = b1[tid];
    if (tid < 32)  biases[640 + tid] = b2[tid];
    if (tid < 128) biases[672 + tid] = db1[tid];
    if (tid < 256) biases[800 + tid] = db2[tid];

    // stage x tile -> bf16 LDS
    {
        const float4* xg = (const float4*)(x + (size_t)b0 * SAMPLE);
        #pragma unroll
        for (int it = 0; it < (TB * SAMPLE / 4) / NT; ++it) {
            int v = it * NT + tid;             // float4 index
            float4 f = xg[v];
            int row = v >> 7;                  // 128 float4 per row
            int cp  = (v & 127) * 4;
            u16* p = xs + row * 520 + cp;
            u16 t4[4] = { f2b(f.x), f2b(f.y), f2b(f.z), f2b(f.w) };
            *(unsigned long long*)p = *(unsigned long long*)t4;
        }
    }
    __syncthreads();

    // A: h1 = relu(x @ Wg + gb)        [16,512] x [512,512]
    mfma_phase<16, 32, 4>(wave, lane, xs, 520, ws + WGP_OFF,  biases,       h1, 520);
    __syncthreads();
    // B: h2 = relu(h1 @ w1 + b1)       [16,512] x [512,128]  (h2 overlays dead xs)
    mfma_phase<16, 8, 1>(wave, lane, h1, 520, ws + W1P_OFF,  biases + 512, h2, 136);
    __syncthreads();
    // C: z = relu(h2 @ w2 + b2)        [16,128] x [128,32]
    mfma_phase<4, 2, 1>(wave, lane, h2, 136, ws + W2P_OFF,  biases + 640, zz, 40);
    __syncthreads();
    // D: d1 = relu(z @ dw1 + db1)      [16,32] x [32,128]
    mfma_phase<1, 8, 1>(wave, lane, zz, 40,  ws + DW1P_OFF, biases + 672, d1, 136);
    __syncthreads();
    // E: d2 = relu(d1 @ dw2 + db2)     [16,128] x [128,256]
    mfma_phase<4, 16, 2>(wave, lane, d1, 136, ws + DW2P_OFF, biases + 800, d2, 264);
    __syncthreads();

    // F: out = sigmoid(d2 @ dw3 + db3) [16,256] x [256,512] -> global fp32
    {
        const u16* arow = d2 + (lane & 15) * 264 + (lane >> 4) * 8;
        const u16* pW = ws + DW3P_OFF;
        f32x4 acc[4];
        #pragma unroll
        for (int i = 0; i < 4; ++i) acc[i] = (f32x4){0.f, 0.f, 0.f, 0.f};
        #pragma unroll
        for (int kt = 0; kt < 8; ++kt) {
            s16x8 a = *(const s16x8*)(arow + kt * 32);
            #pragma unroll
            for (int i = 0; i < 4; ++i) {
                int nt = wave + 8 * i;
                s16x8 b = *(const s16x8*)(pW + (size_t)((nt * 8 + kt) * 64 + lane) * 8);
                acc[i] = __builtin_amdgcn_mfma_f32_16x16x32_bf16(a, b, acc[i], 0, 0, 0);
            }
        }
        #pragma unroll
        for (int i = 0; i < 4; ++i) {
            int nt = wave + 8 * i;
            int col = nt * 16 + (lane & 15);
            float bs = biases[1056 + col];
            #pragma unroll
            for (int r = 0; r < 4; ++r) {
                int row = (lane >> 4) * 4 + r;
                float v = acc[i][r] + bs;
                out[(size_t)(b0 + row) * SAMPLE + col] = 1.f / (1.f + __expf(-v));
            }
        }
    }
}

extern "C" void kernel_launch(void* const* d_in, const int* in_sizes, int n_in,
                              void* d_out, int out_size, void* d_ws, size_t ws_size,
                              hipStream_t stream) {
    const float* x   = (const float*)d_in[0];
    const float* gw  = (const float*)d_in[1];
    const float* gb  = (const float*)d_in[2];
    const float* w1  = (const float*)d_in[3];
    const float* b1  = (const float*)d_in[4];
    const float* w2  = (const float*)d_in[5];
    const float* b2  = (const float*)d_in[6];
    const float* dw1 = (const float*)d_in[7];
    const float* db1 = (const float*)d_in[8];
    const float* dw2 = (const float*)d_in[9];
    const float* db2 = (const float*)d_in[10];
    const float* dw3 = (const float*)d_in[11];
    const float* db3 = (const float*)d_in[12];
    const int* idx   = (const int*)d_in[13];
    const float* mask= (const float*)d_in[14];
    float* out = (float*)d_out;
    u16* ws = (u16*)d_ws;

    const int B  = in_sizes[0] / SAMPLE;     // 8192
    const int G  = in_sizes[2];              // 510
    const int K  = in_sizes[1] / G;          // 28

    build_ws<<<512, 256, 0, stream>>>(w1, w2, dw1, dw2, dw3,
                                      gw, mask, idx, ws, G, K);
    ae_mfma<<<B / TB, NT, 0, stream>>>(x, gb, b1, b2, db1, db2, db3, ws, out);
}